// Round 6
// baseline (2358.099 us; speedup 1.0000x reference)
//
#include <hip/hip_runtime.h>
#include <cstdint>
#include <cstddef>

#define BATCH   4096
#define IN_DIM  1024
#define HID     16384
#define KSEL    32

// ---------------------------------------------------------------------------
// Kernel 1: encoder GEMM  C[B,H] = X[B,D] @ W_enc[H,D]^T + b_enc
// fp32, 128x128 tile, BK=16, 256 threads, 8x8 micro-tile.
//
// NUMERICS CONTRACT (do not change): per output element, fmaf over k in
// strictly ascending order with a single accumulator, then + bias. Top-k
// rank-32 boundary gaps are ~0.007; ANY accumulation reordering (bf16x3 MFMA
// in r4: absmax 4.31 = selection flip) fails. MFMA is unusable here.
//
// Structure (r5 post-mortem): effective workgroup LDS pool is ~64 KB/CU
// (r1 16.9KB->3.8 blocks/CU, r5 32KB->2 blocks/CU). So: DOUBLE-BUFFERED
// global_load_lds staging (prefetch costs 0 VGPRs -> no r2/r3 acc spill),
// BK=16 so 2x(8+8)KB = 32KB -> 2 blocks/CU. Prefetch of tile s+1 issues
// before compute on tile s (2048 VALU cyc >> ~900 cyc HBM latency), so the
// structural vmcnt(0)-before-s_barrier finds loads already complete.
// 16B chunks XOR-swizzled by ((row>>3)&3): A-reads conflict-free (broadcast),
// B-reads 4-way (1.58x on half the LDS traffic - LDS pipe still has slack).
// ---------------------------------------------------------------------------
#define BKK 16

__global__ __launch_bounds__(256, 2)
void enc_gemm(const float* __restrict__ X, const float* __restrict__ W,
              const float* __restrict__ bias, float* __restrict__ C)
{
    __shared__ __align__(16) float As[2][128 * BKK];   // 8 KB per buffer
    __shared__ __align__(16) float Bs[2][128 * BKK];

    const int bn = blockIdx.x;   // HID/128 = 128
    const int bm = blockIdx.y;   // BATCH/128 = 32
    const int t  = threadIdx.x;
    const int tx = t & 15;       // 8 cols each
    const int ty = t >> 4;       // 8 rows each

    float acc[8][8];
#pragma unroll
    for (int i = 0; i < 8; ++i)
#pragma unroll
        for (int j = 0; j < 8; ++j) acc[i][j] = 0.f;

    const float* Xb = X + (size_t)(bm * 128) * IN_DIM;
    const float* Wb = W + (size_t)(bn * 128) * IN_DIM;

    // stage one 128x16 tile pair into buffer `buf` (2 x 16B DMA per thread
    // per matrix; slot s holds row m=s>>2, global chunk (s&3)^((m>>3)&3))
    auto stage = [&](int buf, int k0) {
#pragma unroll
        for (int p = 0; p < 2; ++p) {
            const int s  = p * 256 + t;            // 0..511
            const int m  = s >> 2;                 // 0..127
            const int gc = (s & 3) ^ ((m >> 3) & 3);
            __builtin_amdgcn_global_load_lds(
                (const __attribute__((address_space(1))) void*)(Xb + (size_t)m * IN_DIM + k0 + gc * 4),
                (__attribute__((address_space(3))) void*)(&As[buf][s * 4]), 16, 0, 0);
            __builtin_amdgcn_global_load_lds(
                (const __attribute__((address_space(1))) void*)(Wb + (size_t)m * IN_DIM + k0 + gc * 4),
                (__attribute__((address_space(3))) void*)(&Bs[buf][s * 4]), 16, 0, 0);
        }
    };

    stage(0, 0);
    __syncthreads();             // vmcnt(0) drain: tile 0 resident

    const int akey = ty & 3;     // (m>>3)&3 for m = ty*8+i, i<8
    const int bkey = tx & 3;     // (n>>3)&3 for n = tx*8+j, j<8
    const int NS = IN_DIM / BKK; // 64

    for (int s = 0; s < NS; ++s) {
        const int cur = s & 1;
        // prefetch tile s+1 into the other buffer BEFORE compute; the buffer
        // being overwritten was last read in iteration s-1, protected by the
        // barrier at the end of s-1. Zero VGPR cost (direct-to-LDS DMA).
        if (s + 1 < NS) stage(cur ^ 1, (s + 1) * BKK);

        // ---- compute on buffer cur: 4 groups of 4 consecutive k
#pragma unroll
        for (int kq = 0; kq < 4; ++kq) {
            float4 a4[8], b4[8];
#pragma unroll
            for (int i = 0; i < 8; ++i)
                a4[i] = *(const float4*)(&As[cur][(ty * 8 + i) * BKK + ((kq ^ akey) * 4)]);
#pragma unroll
            for (int j = 0; j < 8; ++j)
                b4[j] = *(const float4*)(&Bs[cur][(tx * 8 + j) * BKK + ((kq ^ bkey) * 4)]);
            // k ascending within the group: components x,y,z,w in order.
            // Chain per (i,j) identical to the validated r1/r5 kernels.
#pragma unroll
            for (int i = 0; i < 8; ++i)
#pragma unroll
                for (int j = 0; j < 8; ++j)
                    acc[i][j] = fmaf(a4[i].x, b4[j].x, acc[i][j]);
#pragma unroll
            for (int i = 0; i < 8; ++i)
#pragma unroll
                for (int j = 0; j < 8; ++j)
                    acc[i][j] = fmaf(a4[i].y, b4[j].y, acc[i][j]);
#pragma unroll
            for (int i = 0; i < 8; ++i)
#pragma unroll
                for (int j = 0; j < 8; ++j)
                    acc[i][j] = fmaf(a4[i].z, b4[j].z, acc[i][j]);
#pragma unroll
            for (int i = 0; i < 8; ++i)
#pragma unroll
                for (int j = 0; j < 8; ++j)
                    acc[i][j] = fmaf(a4[i].w, b4[j].w, acc[i][j]);
        }
        // drains prefetch (long since arrived) + guards both buffers
        __syncthreads();
    }

    const int col0 = bn * 128 + tx * 8;
    float bv[8];
#pragma unroll
    for (int j = 0; j < 8; ++j) bv[j] = bias[col0 + j];
#pragma unroll
    for (int i = 0; i < 8; ++i) {
        const size_t rowoff = (size_t)(bm * 128 + ty * 8 + i) * HID + col0;
        float4 o0, o1;
        o0.x = acc[i][0] + bv[0]; o0.y = acc[i][1] + bv[1];
        o0.z = acc[i][2] + bv[2]; o0.w = acc[i][3] + bv[3];
        o1.x = acc[i][4] + bv[4]; o1.y = acc[i][5] + bv[5];
        o1.z = acc[i][6] + bv[6]; o1.w = acc[i][7] + bv[7];
        *(float4*)(C + rowoff)     = o0;
        *(float4*)(C + rowoff + 4) = o1;
    }
}

// ---------------------------------------------------------------------------
// Kernel 2 (v4, unchanged from r5 - validated): per-row exact top-32 by
// |value|, 4-level radix select. Row cached in LDS; wave-shuffle suffix scan.
// ---------------------------------------------------------------------------
__global__ __launch_bounds__(256)
void topk_rows(float* __restrict__ E, int* __restrict__ idx_out,
               float* __restrict__ val_out)
{
    const int row = blockIdx.x;
    float* p = E + (size_t)row * HID;
    const int t    = threadIdx.x;
    const int lane = t & 63;
    const int wid  = t >> 6;

    __shared__ __align__(16) float row_s[HID];   // 64 KB row cache
    __shared__ unsigned h8[8][257];
    __shared__ unsigned hist[256];
    __shared__ unsigned wsum[4];
    __shared__ unsigned s_prefix;
    __shared__ int s_rank, s_eq, s_cnt;

#pragma unroll
    for (int c = 0; c < 16; ++c) {
        const int s = c * 256 + t;
        __builtin_amdgcn_global_load_lds(
            (const __attribute__((address_space(1))) void*)(p + (size_t)s * 4),
            (__attribute__((address_space(3))) void*)(row_s + s * 4), 16, 0, 0);
    }
    for (int i = t; i < 8 * 257; i += 256) ((unsigned*)h8)[i] = 0u;
    if (t == 0) { s_rank = KSEL; s_prefix = 0u; s_eq = 0; s_cnt = 0; }
    __syncthreads();

    unsigned* myh = h8[t & 7];
#pragma unroll
    for (int c = 0; c < 16; ++c) {
        const float4 v = *(const float4*)(row_s + (c * 256 + t) * 4);
        const float vv[4] = {v.x, v.y, v.z, v.w};
#pragma unroll
        for (int j = 0; j < 4; ++j)
            atomicAdd(&myh[(__float_as_uint(vv[j]) & 0x7FFFFFFFu) >> 23], 1u);
    }
    __syncthreads();

    const int psh_arr[4]  = {31, 23, 15, 7};
    const int sh_arr[4]   = {23, 15, 7, 0};
    const unsigned msk[4] = {255u, 255u, 255u, 127u};
    const int bits_arr[4] = {8, 8, 8, 7};

#pragma unroll
    for (int lvl = 0; lvl < 4; ++lvl) {
        const int r = s_rank;
        const unsigned pfx = s_prefix;

        unsigned mycnt;
        if (lvl == 0) {
            unsigned m = 0;
#pragma unroll
            for (int c = 0; c < 8; ++c) m += h8[c][t];
            mycnt = m;
        } else {
            hist[t] = 0u;
            __syncthreads();
            const int psh = psh_arr[lvl];
            const int sh  = sh_arr[lvl];
#pragma unroll
            for (int c = 0; c < 16; ++c) {
                const float4 v = *(const float4*)(row_s + (c * 256 + t) * 4);
                const float vv[4] = {v.x, v.y, v.z, v.w};
#pragma unroll
                for (int j = 0; j < 4; ++j) {
                    const unsigned k = __float_as_uint(vv[j]) & 0x7FFFFFFFu;
                    if ((k >> psh) == pfx)
                        atomicAdd(&hist[(k >> sh) & msk[lvl]], 1u);
                }
            }
            __syncthreads();
            mycnt = hist[t];
        }

        unsigned sv = mycnt;
#pragma unroll
        for (int off = 1; off < 64; off <<= 1) {
            const unsigned u = __shfl_down(sv, off, 64);
            sv += (lane + off < 64) ? u : 0u;
        }
        if (lane == 0) wsum[wid] = sv;
        __syncthreads();
        unsigned above = 0;
        for (int ww = wid + 1; ww < 4; ++ww) above += wsum[ww];
        const unsigned suff  = sv + above;
        const unsigned suffn = suff - mycnt;
        if (suff >= (unsigned)r && suffn < (unsigned)r) {
            s_rank   = r - (int)suffn;
            s_prefix = (pfx << bits_arr[lvl]) | (unsigned)t;
        }
        __syncthreads();
    }

    const unsigned vkey = s_prefix;
    const int eq_need   = s_rank;

#pragma unroll
    for (int c = 0; c < 16; ++c) {
        const int i0 = (c * 256 + t) * 4;
        const float4 v = *(const float4*)(row_s + i0);
        float vv[4] = {v.x, v.y, v.z, v.w};
#pragma unroll
        for (int j = 0; j < 4; ++j) {
            const unsigned k = __float_as_uint(vv[j]) & 0x7FFFFFFFu;
            bool keep = false;
            if (k > vkey) keep = true;
            else if (k == vkey) {
                const int slot = atomicAdd(&s_eq, 1);
                if (slot < eq_need) keep = true;
            }
            if (keep) {
                const int ls = atomicAdd(&s_cnt, 1);
                idx_out[row * KSEL + ls] = i0 + j;
                val_out[row * KSEL + ls] = vv[j];
            } else {
                vv[j] = 0.f;
            }
        }
        float4 o; o.x = vv[0]; o.y = vv[1]; o.z = vv[2]; o.w = vv[3];
        *(float4*)(p + i0) = o;
    }
}

// ---------------------------------------------------------------------------
// Kernel 3: transpose W_dec [1024,16384] -> WdT [16384,1024] (ws scratch)
// ---------------------------------------------------------------------------
__global__ __launch_bounds__(256)
void transpose_wdec(const float* __restrict__ Wd, float* __restrict__ WdT)
{
    __shared__ float tile[32][33];
    const int bx = blockIdx.x;
    const int by = blockIdx.y;
    const int t  = threadIdx.x;
    const int lx = t & 31, ly = t >> 5;
#pragma unroll
    for (int r = 0; r < 32; r += 8)
        tile[ly + r][lx] = Wd[(size_t)(by * 32 + ly + r) * HID + bx * 32 + lx];
    __syncthreads();
#pragma unroll
    for (int r = 0; r < 32; r += 8)
        WdT[(size_t)(bx * 32 + ly + r) * IN_DIM + by * 32 + lx] = tile[lx][ly + r];
}

// ---------------------------------------------------------------------------
// Kernel 4: sparse decode  decoded[b,:] = sum_i val_i * WdT[idx_i,:] + b_dec
// ---------------------------------------------------------------------------
__global__ __launch_bounds__(256)
void decode_rows(const float* __restrict__ WdT, const float* __restrict__ bd,
                 const int* __restrict__ idxs, const float* __restrict__ vals,
                 float* __restrict__ out)
{
    const int row = blockIdx.x;
    const int d   = threadIdx.x * 4;
    float4 acc = *(const float4*)(bd + d);
    for (int i = 0; i < KSEL; ++i) {
        const int   j = idxs[row * KSEL + i];
        const float v = vals[row * KSEL + i];
        const float4 w = *(const float4*)(WdT + (size_t)j * IN_DIM + d);
        acc.x = fmaf(v, w.x, acc.x);
        acc.y = fmaf(v, w.y, acc.y);
        acc.z = fmaf(v, w.z, acc.z);
        acc.w = fmaf(v, w.w, acc.w);
    }
    *(float4*)(out + (size_t)row * IN_DIM + d) = acc;
}

__global__ __launch_bounds__(256)
void decode_rows_noT(const float* __restrict__ Wd, const float* __restrict__ bd,
                     const int* __restrict__ idxs, const float* __restrict__ vals,
                     float* __restrict__ out)
{
    const int row = blockIdx.x;
    const int d0  = threadIdx.x * 4;
    float acc[4];
#pragma unroll
    for (int q = 0; q < 4; ++q) acc[q] = bd[d0 + q];
    for (int i = 0; i < KSEL; ++i) {
        const int   j = idxs[row * KSEL + i];
        const float v = vals[row * KSEL + i];
#pragma unroll
        for (int q = 0; q < 4; ++q)
            acc[q] = fmaf(v, Wd[(size_t)(d0 + q) * HID + j], acc[q]);
    }
#pragma unroll
    for (int q = 0; q < 4; ++q) out[(size_t)row * IN_DIM + d0 + q] = acc[q];
}

// ---------------------------------------------------------------------------
extern "C" void kernel_launch(void* const* d_in, const int* in_sizes, int n_in,
                              void* d_out, int out_size, void* d_ws, size_t ws_size,
                              hipStream_t stream)
{
    const float* x     = (const float*)d_in[0];
    const float* W_enc = (const float*)d_in[1];
    const float* b_enc = (const float*)d_in[2];
    const float* W_dec = (const float*)d_in[3];
    const float* b_dec = (const float*)d_in[4];

    float* out     = (float*)d_out;
    float* sparse  = out;                                // [4096][16384]
    float* decoded = out + (size_t)BATCH * HID;          // [4096][1024]

    const size_t list_bytes = (size_t)BATCH * KSEL * 4;
    const size_t wdt_bytes  = (size_t)HID * IN_DIM * 4;
    int*   idx_l = (int*)d_ws;
    float* val_l = (float*)((char*)d_ws + list_bytes);
    float* WdT   = (float*)((char*)d_ws + 2 * list_bytes);
    const bool have_wdt = ws_size >= 2 * list_bytes + wdt_bytes;

    enc_gemm<<<dim3(HID / 128, BATCH / 128), 256, 0, stream>>>(x, W_enc, b_enc, sparse);

    topk_rows<<<BATCH, 256, 0, stream>>>(sparse, idx_l, val_l);

    if (have_wdt) {
        transpose_wdec<<<dim3(HID / 32, IN_DIM / 32), 256, 0, stream>>>(W_dec, WdT);
        decode_rows<<<BATCH, 256, 0, stream>>>(WdT, b_dec, idx_l, val_l, decoded);
    } else {
        decode_rows_noT<<<BATCH, 256, 0, stream>>>(W_dec, b_dec, idx_l, val_l, decoded);
    }
}